// Round 9
// baseline (97.525 us; speedup 1.0000x reference)
//
#include <hip/hip_runtime.h>
#include <hip/hip_fp16.h>

#define B_DIM   128
#define N_IN    16384
#define N_OUT   8192
#define N_EDGES (N_OUT * 64)

#define J_BLK    8                  // outputs (waves) per block
#define THREADS  (J_BLK * 64)       // 512
#define JGROUPS  (N_OUT / J_BLK)    // 1024

__device__ __forceinline__ int lower_bound_dev(const int* __restrict__ a, int n, int v) {
    int lo = 0, hi = n;
    while (lo < hi) {
        int mid = (lo + hi) >> 1;
        if (a[mid] < v) lo = mid + 1; else hi = mid;
    }
    return lo;
}

// One pass over edges: rowptr boundary-scatter + pack meta[e] = {src*rowbytes, w_bits}.
__global__ __launch_bounds__(256) void prep_kernel(const int* __restrict__ dst,
                                                   const int* __restrict__ src,
                                                   const float* __restrict__ w,
                                                   int* __restrict__ rp,
                                                   int2* __restrict__ meta) {
    const int e = blockIdx.x * 256 + threadIdx.x;
    if (e >= N_EDGES) return;
    const int d     = dst[e];
    const int dprev = (e == 0) ? -1 : dst[e - 1];
    for (int j = dprev + 1; j <= d; ++j) rp[j] = e;
    if (e == N_EDGES - 1)
        for (int j = d + 1; j <= N_OUT; ++j) rp[j] = N_EDGES;
    meta[e] = make_int2(src[e] * (B_DIM * 2), __float_as_int(w[e]));
}

// x[B][N_IN] (fp32) -> xTh[N_IN][B] (fp16). Read coalesced, write 128B half2 rows.
__global__ __launch_bounds__(256) void transpose_h_kernel(const float* __restrict__ x,
                                                          __half* __restrict__ xTh) {
    __shared__ float tile[64][33];      // [b_local][i_local]
    const int i0 = blockIdx.x * 32;
    const int b0 = blockIdx.y * 64;
    const int tx = threadIdx.x;         // 0..31
    const int ty = threadIdx.y;         // 0..7
#pragma unroll
    for (int r = 0; r < 64; r += 8)
        tile[ty + r][tx] = x[(size_t)(b0 + ty + r) * N_IN + (i0 + tx)];
    __syncthreads();
    __half2* out = (__half2*)xTh;
#pragma unroll
    for (int rr = 0; rr < 4; ++rr) {
        const int il = rr * 8 + ty;     // i_local 0..31
        const float a = tile[2 * tx][il];
        const float b = tile[2 * tx + 1][il];
        out[(size_t)(i0 + il) * (B_DIM / 2) + (b0 >> 1) + tx] = __floats2half2_rn(a, b);
    }
}

#define FMA8(V, WT)                                                                \
    do {                                                                           \
        const __half2* hp_ = (const __half2*)&(V);                                 \
        _Pragma("unroll")                                                          \
        for (int q = 0; q < 4; ++q) {                                              \
            const float2 f_ = __half22float2(hp_[q]);                              \
            acc[2 * q]     = fmaf(f_.x, (WT), acc[2 * q]);                         \
            acc[2 * q + 1] = fmaf(f_.y, (WT), acc[2 * q + 1]);                     \
        }                                                                          \
    } while (0)

// One WAVE per output j. Lane = (slot = lane>>4 -> edge within quad,
// bl = lane&15 -> 16B of the 256B fp16 row). Per 64-edge chunk: PHASE A issues
// all 16 meta loads + 16 independent float4 gathers into static register
// arrays (fully unrolled -> stays in VGPRs); PHASE B does the cvt+FMA work.
// No launch-bounds throttle: ~120 VGPR -> 16 waves/CU with 16 gathers in
// flight each (~256 KB outstanding per CU, ~2x the round-5 configuration).
__global__ __launch_bounds__(THREADS) void sparse_layer_h3(
        const __half* __restrict__ xTh, const float* __restrict__ bias,
        const int2* __restrict__ meta, const int* __restrict__ rp,
        float* __restrict__ y) {
    __shared__ float tile[J_BLK][132];

    const int tid  = threadIdx.x;
    const int wid  = tid >> 6;
    const int lane = tid & 63;
    const int slot = lane >> 4;         // 0..3
    const int bl   = lane & 15;
    const int j0   = blockIdx.x * J_BLK;
    const int j    = j0 + wid;

    const int e0 = __builtin_amdgcn_readfirstlane(rp[j]);
    const int e1 = __builtin_amdgcn_readfirstlane(rp[j + 1]);

    float acc[8] = {0.f, 0.f, 0.f, 0.f, 0.f, 0.f, 0.f, 0.f};
    const char* xb = (const char*)xTh + bl * 16;

    for (int base = e0; base < e1; base += 64) {
        const int nrem = e1 - base;
        if (nrem >= 64) {
            float4 v[16];
            float  wt[16];
            // PHASE A: 16 independent meta loads + 16 independent gathers.
#pragma unroll
            for (int k = 0; k < 16; ++k) {
                const int2 m = meta[base + 4 * k + slot];
                wt[k] = __int_as_float(m.y);
                v[k]  = *(const float4*)(xb + (size_t)(unsigned)m.x);
            }
            // PHASE B: all FMA work after loads are in flight.
#pragma unroll
            for (int k = 0; k < 16; ++k) FMA8(v[k], wt[k]);
        } else {
            for (int k = 0; 4 * k < nrem; ++k) {
                const int  ee    = base + 4 * k + slot;
                const bool valid = ee < e1;
                const int  ec    = valid ? ee : e0;
                const int2 m     = meta[ec];
                const float wtk  = valid ? __int_as_float(m.y) : 0.f;
                const float4 vk  = *(const float4*)(xb + (size_t)(unsigned)m.x);
                FMA8(vk, wtk);
            }
        }
    }

    // Reduce over the 4 edge slots (lane bits 4..5).
#pragma unroll
    for (int m_ = 16; m_ <= 32; m_ <<= 1)
#pragma unroll
        for (int q = 0; q < 8; ++q) acc[q] += __shfl_xor(acc[q], m_, 64);

    if (slot == 0) {                    // lanes 0..15 hold b = 8*bl .. 8*bl+7
#pragma unroll
        for (int q = 0; q < 8; ++q) tile[wid][8 * bl + q] = acc[q];
    }
    __syncthreads();

    // Coalesced epilogue: 8 consecutive lanes -> 8 consecutive j (32B segments).
#pragma unroll
    for (int i = tid; i < B_DIM * J_BLK; i += THREADS) {
        const int bb = i >> 3;
        const int jj = i & (J_BLK - 1);
        const float v = tile[jj][bb] + bias[j0 + jj];
        y[(size_t)bb * N_OUT + (j0 + jj)] = fmaxf(v, 0.f);
    }
}

// Fallback (no usable workspace): per-output wave, fp32 gathers from row-major x.
__global__ __launch_bounds__(THREADS) void sparse_layer_fallback(
        const float* __restrict__ x, const float* __restrict__ w,
        const float* __restrict__ bias, const int* __restrict__ src,
        const int* __restrict__ dst, float* __restrict__ y) {
    __shared__ float tile[J_BLK][130];
    __shared__ int   srp[J_BLK + 1];

    const int tid  = threadIdx.x;
    const int wid  = tid >> 6;
    const int lane = tid & 63;
    const int j0   = blockIdx.x * J_BLK;

    if (tid <= J_BLK) srp[tid] = lower_bound_dev(dst, N_EDGES, j0 + tid);
    __syncthreads();

    const int e0 = srp[wid], e1 = srp[wid + 1];
    const int b0 = lane * 2;
    float acc0 = 0.f, acc1 = 0.f;
    for (int e = e0; e < e1; ++e) {
        const int   s  = src[e];
        const float wt = w[e];
        acc0 = fmaf(x[(size_t)b0 * N_IN + s], wt, acc0);
        acc1 = fmaf(x[(size_t)(b0 + 1) * N_IN + s], wt, acc1);
    }
    tile[wid][b0]     = acc0;
    tile[wid][b0 + 1] = acc1;
    __syncthreads();
#pragma unroll
    for (int i = tid; i < B_DIM * J_BLK; i += THREADS) {
        const int bb = i >> 3;
        const int jj = i & (J_BLK - 1);
        const float v = tile[jj][bb] + bias[j0 + jj];
        y[(size_t)bb * N_OUT + (j0 + jj)] = fmaxf(v, 0.f);
    }
}

extern "C" void kernel_launch(void* const* d_in, const int* in_sizes, int n_in,
                              void* d_out, int out_size, void* d_ws, size_t ws_size,
                              hipStream_t stream) {
    const float* x    = (const float*)d_in[0];
    const float* w    = (const float*)d_in[1];
    const float* bias = (const float*)d_in[2];
    const int*   esrc = (const int*)d_in[3];
    const int*   edst = (const int*)d_in[4];
    float*       y    = (float*)d_out;

    // ws layout: rp [0, 33KB) | meta [64KB, 64KB+4MB) | xTh [next, +4MB)
    const size_t META_OFF   = 65536;
    const size_t META_BYTES = (size_t)N_EDGES * sizeof(int2);
    const size_t XT_OFF     = META_OFF + META_BYTES;
    const size_t XT_BYTES   = (size_t)N_IN * B_DIM * sizeof(__half);

    const bool has_ws = ws_size >= XT_OFF + XT_BYTES;

    int*    rp   = (int*)d_ws;
    int2*   meta = (int2*)((char*)d_ws + META_OFF);
    __half* xTh  = (__half*)((char*)d_ws + XT_OFF);

    if (has_ws) {
        prep_kernel<<<dim3((N_EDGES + 255) / 256), 256, 0, stream>>>(edst, esrc, w, rp, meta);
        transpose_h_kernel<<<dim3(N_IN / 32, B_DIM / 64), dim3(32, 8), 0, stream>>>(x, xTh);
        sparse_layer_h3<<<dim3(JGROUPS), THREADS, 0, stream>>>(xTh, bias, meta, rp, y);
    } else {
        sparse_layer_fallback<<<dim3(N_OUT / J_BLK), THREADS, 0, stream>>>(x, w, bias, esrc, edst, y);
    }
}

// Round 10
// 97.284 us; speedup vs baseline: 1.0025x; 1.0025x over previous
//
#include <hip/hip_runtime.h>
#include <hip/hip_fp16.h>

#define B_DIM   128
#define N_IN    16384
#define N_OUT   8192
#define N_EDGES (N_OUT * 64)

#define J_BLK    8                  // outputs (waves) per block
#define THREADS  (J_BLK * 64)       // 512
#define JGROUPS  (N_OUT / J_BLK)    // 1024

__device__ __forceinline__ int lower_bound_dev(const int* __restrict__ a, int n, int v) {
    int lo = 0, hi = n;
    while (lo < hi) {
        int mid = (lo + hi) >> 1;
        if (a[mid] < v) lo = mid + 1; else hi = mid;
    }
    return lo;
}

// rp[j] = first edge index with dst >= j (j in [0, N_OUT]), via boundary scatter.
__global__ void build_rowptr_kernel(const int* __restrict__ dst, int* __restrict__ rp) {
    const int e = blockIdx.x * blockDim.x + threadIdx.x;
    if (e >= N_EDGES) return;
    const int d     = dst[e];
    const int dprev = (e == 0) ? -1 : dst[e - 1];
    for (int j = dprev + 1; j <= d; ++j) rp[j] = e;
    if (e == N_EDGES - 1)
        for (int j = d + 1; j <= N_OUT; ++j) rp[j] = N_EDGES;
}

// Per-output edge sort by src (ascending) -> ssrc/sw. One WAVE per output j,
// bitonic-128 with 2 elements/lane. Keys unique: src*128 + original slot.
// Sum is commutative so reordering is semantics-preserving; goal is an
// ascending sweep through xTh per wave (DRAM/L3/L2 ordering locality).
__global__ __launch_bounds__(512) void sort_kernel(const int* __restrict__ src,
                                                   const float* __restrict__ w,
                                                   const int* __restrict__ rp,
                                                   int* __restrict__ ssrc,
                                                   float* __restrict__ sw) {
    const int gw   = (blockIdx.x * 512 + threadIdx.x) >> 6;   // global wave id = j
    const int lane = threadIdx.x & 63;
    if (gw >= N_OUT) return;
    const int e0 = rp[gw], e1 = rp[gw + 1];
    const int n  = e1 - e0;
    if (n <= 0) return;
    if (n > 128) {   // statistically impossible (mean 64, std 8); correctness fallback
        for (int e = e0 + lane; e < e1; e += 64) { ssrc[e] = src[e]; sw[e] = w[e]; }
        return;
    }
    int   k0 = 0x7FFFFFFF, k1 = 0x7FFFFFFF;
    float w0 = 0.f,        w1 = 0.f;
    if (lane < n)      { k0 = (src[e0 + lane]      << 7) | lane;        w0 = w[e0 + lane]; }
    if (lane + 64 < n) { k1 = (src[e0 + 64 + lane] << 7) | (64 + lane); w1 = w[e0 + 64 + lane]; }

#pragma unroll
    for (int k = 2; k <= 128; k <<= 1) {
#pragma unroll
        for (int jj = 64; jj > 0; jj >>= 1) {
            if (jj >= k) continue;
            if (jj == 64) {
                // only at k=128: pair (lane, lane+64), ascending -> (min, max)
                const bool swp = k1 < k0;
                const int   lo = swp ? k1 : k0, hi = swp ? k0 : k1;
                const float wl = swp ? w1 : w0, wh = swp ? w0 : w1;
                k0 = lo; k1 = hi; w0 = wl; w1 = wh;
            } else {
                const bool lower = (lane & jj) == 0;
                const bool up0   = ((lane & k) == 0);
                const bool up1   = (((lane + 64) & k) == 0);
                int   pk0 = __shfl_xor(k0, jj, 64);
                float pw0 = __shfl_xor(w0, jj, 64);
                const bool take0 = (lower == up0) ? (pk0 < k0) : (pk0 > k0);
                if (take0) { k0 = pk0; w0 = pw0; }
                int   pk1 = __shfl_xor(k1, jj, 64);
                float pw1 = __shfl_xor(w1, jj, 64);
                const bool take1 = (lower == up1) ? (pk1 < k1) : (pk1 > k1);
                if (take1) { k1 = pk1; w1 = pw1; }
            }
        }
    }
    if (lane < n)      { ssrc[e0 + lane]      = k0 >> 7; sw[e0 + lane]      = w0; }
    if (lane + 64 < n) { ssrc[e0 + 64 + lane] = k1 >> 7; sw[e0 + 64 + lane] = w1; }
}

// x[B][N_IN] (fp32) -> xTh[N_IN][B] (fp16). Read coalesced, write 128B half2 rows.
__global__ __launch_bounds__(256) void transpose_h_kernel(const float* __restrict__ x,
                                                          __half* __restrict__ xTh) {
    __shared__ float tile[64][33];      // [b_local][i_local]
    const int i0 = blockIdx.x * 32;
    const int b0 = blockIdx.y * 64;
    const int tx = threadIdx.x;         // 0..31
    const int ty = threadIdx.y;         // 0..7
#pragma unroll
    for (int r = 0; r < 64; r += 8)
        tile[ty + r][tx] = x[(size_t)(b0 + ty + r) * N_IN + (i0 + tx)];
    __syncthreads();
    __half2* out = (__half2*)xTh;
#pragma unroll
    for (int rr = 0; rr < 4; ++rr) {
        const int il = rr * 8 + ty;     // i_local 0..31
        const float a = tile[2 * tx][il];
        const float b = tile[2 * tx + 1][il];
        out[(size_t)(i0 + il) * (B_DIM / 2) + (b0 >> 1) + tx] = __floats2half2_rn(a, b);
    }
}

// EXACT round-5 main kernel (best measured: 86.8us), reading sorted ssrc/sw.
// One WAVE per output j. Lane = (slot = lane>>4 -> edge within quad, bl =
// lane&15 -> 16B of the 256B fp16 row). 4 edges per gather instruction, fp32
// accumulate, 2-step shfl_xor reduce over slots, LDS-transposed epilogue.
__global__ __launch_bounds__(THREADS, 8) void sparse_layer_h(
        const __half* __restrict__ xTh, const float* __restrict__ sw,
        const float* __restrict__ bias, const int* __restrict__ ssrc,
        const int* __restrict__ rp, float* __restrict__ y) {
    __shared__ float tile[J_BLK][132];  // 132: 16B-aligned rows

    const int tid  = threadIdx.x;
    const int wid  = tid >> 6;
    const int lane = tid & 63;
    const int slot = lane >> 4;         // 0..3
    const int bl   = lane & 15;         // 16B chunk -> batch cols 8*bl .. 8*bl+7
    const int j0   = blockIdx.x * J_BLK;
    const int j    = j0 + wid;

    const int e0 = __builtin_amdgcn_readfirstlane(rp[j]);
    const int e1 = __builtin_amdgcn_readfirstlane(rp[j + 1]);

    float acc[8] = {0.f, 0.f, 0.f, 0.f, 0.f, 0.f, 0.f, 0.f};
    const char* xbase = (const char*)xTh + bl * 16;   // + row*256B

#pragma unroll 4
    for (int e = e0; e < e1; e += 4) {
        const int  ee    = e + slot;
        const bool valid = ee < e1;
        const int  ec    = valid ? ee : e0;           // e0 < e1 inside loop
        const int  s     = ssrc[ec];
        const float wt   = valid ? sw[ec] : 0.f;
        const float4 raw = *(const float4*)(xbase + (size_t)s * (B_DIM * 2));
        const __half2* hp = (const __half2*)&raw;
#pragma unroll
        for (int q = 0; q < 4; ++q) {
            const float2 f = __half22float2(hp[q]);
            acc[2 * q]     = fmaf(f.x, wt, acc[2 * q]);
            acc[2 * q + 1] = fmaf(f.y, wt, acc[2 * q + 1]);
        }
    }

    // Reduce over the 4 edge slots (lane bits 4..5).
#pragma unroll
    for (int m = 16; m <= 32; m <<= 1)
#pragma unroll
        for (int q = 0; q < 8; ++q) acc[q] += __shfl_xor(acc[q], m, 64);

    if (slot == 0) {                    // lanes 0..15 hold b = 8*bl .. 8*bl+7
#pragma unroll
        for (int q = 0; q < 8; ++q) tile[wid][8 * bl + q] = acc[q];
    }
    __syncthreads();

    // Coalesced epilogue: 8 consecutive lanes -> 8 consecutive j (32B segments).
#pragma unroll
    for (int i = tid; i < B_DIM * J_BLK; i += THREADS) {
        const int bb = i >> 3;
        const int jj = i & (J_BLK - 1);
        const float v = tile[jj][bb] + bias[j0 + jj];
        y[(size_t)bb * N_OUT + (j0 + jj)] = fmaxf(v, 0.f);
    }
}

// Fallback (no usable workspace): per-output wave, fp32 gathers from row-major x.
__global__ __launch_bounds__(THREADS) void sparse_layer_fallback(
        const float* __restrict__ x, const float* __restrict__ w,
        const float* __restrict__ bias, const int* __restrict__ src,
        const int* __restrict__ dst, float* __restrict__ y) {
    __shared__ float tile[J_BLK][130];
    __shared__ int   srp[J_BLK + 1];

    const int tid  = threadIdx.x;
    const int wid  = tid >> 6;
    const int lane = tid & 63;
    const int j0   = blockIdx.x * J_BLK;

    if (tid <= J_BLK) srp[tid] = lower_bound_dev(dst, N_EDGES, j0 + tid);
    __syncthreads();

    const int e0 = srp[wid], e1 = srp[wid + 1];
    const int b0 = lane * 2;
    float acc0 = 0.f, acc1 = 0.f;
    for (int e = e0; e < e1; ++e) {
        const int   s  = src[e];
        const float wt = w[e];
        acc0 = fmaf(x[(size_t)b0 * N_IN + s], wt, acc0);
        acc1 = fmaf(x[(size_t)(b0 + 1) * N_IN + s], wt, acc1);
    }
    tile[wid][b0]     = acc0;
    tile[wid][b0 + 1] = acc1;
    __syncthreads();
#pragma unroll
    for (int i = tid; i < B_DIM * J_BLK; i += THREADS) {
        const int bb = i >> 3;
        const int jj = i & (J_BLK - 1);
        const float v = tile[jj][bb] + bias[j0 + jj];
        y[(size_t)bb * N_OUT + (j0 + jj)] = fmaxf(v, 0.f);
    }
}

extern "C" void kernel_launch(void* const* d_in, const int* in_sizes, int n_in,
                              void* d_out, int out_size, void* d_ws, size_t ws_size,
                              hipStream_t stream) {
    const float* x    = (const float*)d_in[0];
    const float* w    = (const float*)d_in[1];
    const float* bias = (const float*)d_in[2];
    const int*   esrc = (const int*)d_in[3];
    const int*   edst = (const int*)d_in[4];
    float*       y    = (float*)d_out;

    // ws layout: rp [0,33KB) | ssrc [64KB,+2MB) | sw [+2MB) | xTh [+4MB)
    const size_t SSRC_OFF = 65536;
    const size_t SSRC_BY  = (size_t)N_EDGES * sizeof(int);
    const size_t SW_OFF   = SSRC_OFF + SSRC_BY;
    const size_t SW_BY    = (size_t)N_EDGES * sizeof(float);
    const size_t XT_OFF   = SW_OFF + SW_BY;
    const size_t XT_BYTES = (size_t)N_IN * B_DIM * sizeof(__half);

    const bool has_ws = ws_size >= XT_OFF + XT_BYTES;

    int*    rp   = (int*)d_ws;
    int*    ssrc = (int*)((char*)d_ws + SSRC_OFF);
    float*  sw   = (float*)((char*)d_ws + SW_OFF);
    __half* xTh  = (__half*)((char*)d_ws + XT_OFF);

    if (has_ws) {
        build_rowptr_kernel<<<(N_EDGES + 255) / 256, 256, 0, stream>>>(edst, rp);
        sort_kernel<<<dim3((N_OUT * 64 + 511) / 512), 512, 0, stream>>>(esrc, w, rp, ssrc, sw);
        transpose_h_kernel<<<dim3(N_IN / 32, B_DIM / 64), dim3(32, 8), 0, stream>>>(x, xTh);
        sparse_layer_h<<<dim3(JGROUPS), THREADS, 0, stream>>>(xTh, sw, bias, ssrc, rp, y);
    } else {
        sparse_layer_fallback<<<dim3(N_OUT / J_BLK), THREADS, 0, stream>>>(x, w, bias, esrc, edst, y);
    }
}

// Round 11
// 90.975 us; speedup vs baseline: 1.0720x; 1.0693x over previous
//
#include <hip/hip_runtime.h>
#include <hip/hip_fp16.h>

#define B_DIM   128
#define N_IN    16384
#define N_OUT   8192
#define N_EDGES (N_OUT * 64)

#define J_BLK    8                  // outputs (waves) per block
#define THREADS  (J_BLK * 64)       // 512
#define JGROUPS  (N_OUT / J_BLK)    // 1024

__device__ __forceinline__ int lower_bound_dev(const int* __restrict__ a, int n, int v) {
    int lo = 0, hi = n;
    while (lo < hi) {
        int mid = (lo + hi) >> 1;
        if (a[mid] < v) lo = mid + 1; else hi = mid;
    }
    return lo;
}

// rp[j] = first edge index with dst >= j (j in [0, N_OUT]), via boundary scatter.
__global__ void build_rowptr_kernel(const int* __restrict__ dst, int* __restrict__ rp) {
    const int e = blockIdx.x * blockDim.x + threadIdx.x;
    if (e >= N_EDGES) return;
    const int d     = __builtin_nontemporal_load(dst + e);
    const int dprev = (e == 0) ? -1 : __builtin_nontemporal_load(dst + e - 1);
    for (int j = dprev + 1; j <= d; ++j) rp[j] = e;
    if (e == N_EDGES - 1)
        for (int j = d + 1; j <= N_OUT; ++j) rp[j] = N_EDGES;
}

// x[B][N_IN] (fp32) -> xTh[N_IN][B] (fp16). Read coalesced (non-temporal: x is
// streamed once), write 128B half2 rows (normal stores: xTh is the reused set,
// we WANT it resident in L2/L3).
__global__ __launch_bounds__(256) void transpose_h_kernel(const float* __restrict__ x,
                                                          __half* __restrict__ xTh) {
    __shared__ float tile[64][33];      // [b_local][i_local]
    const int i0 = blockIdx.x * 32;
    const int b0 = blockIdx.y * 64;
    const int tx = threadIdx.x;         // 0..31
    const int ty = threadIdx.y;         // 0..7
#pragma unroll
    for (int r = 0; r < 64; r += 8)
        tile[ty + r][tx] = __builtin_nontemporal_load(&x[(size_t)(b0 + ty + r) * N_IN + (i0 + tx)]);
    __syncthreads();
    __half2* out = (__half2*)xTh;
#pragma unroll
    for (int rr = 0; rr < 4; ++rr) {
        const int il = rr * 8 + ty;     // i_local 0..31
        const float a = tile[2 * tx][il];
        const float b = tile[2 * tx + 1][il];
        out[(size_t)(i0 + il) * (B_DIM / 2) + (b0 >> 1) + tx] = __floats2half2_rn(a, b);
    }
}

// EXACT round-5 main kernel (best measured: 86.8us) + non-temporal hints on
// every streamed-once access (src, w, y). Theory: the streaming edge metadata
// (~8 MB) and y writes (4 MB) were evicting the 4 MB xTh gather set from the
// per-XCD L2 (thrash), forcing gathers to L3/HBM at random-access rates.
// nt loads/stores bypass cache pollution; gather loads stay cached.
// One WAVE per output j. Lane = (slot = lane>>4 -> edge within quad,
// bl = lane&15 -> 16B of the 256B fp16 row). 4 edges per gather instruction,
// fp32 accumulate, 2-step shfl_xor reduce over slots, LDS-transposed epilogue.
__global__ __launch_bounds__(THREADS, 8) void sparse_layer_h(
        const __half* __restrict__ xTh, const float* __restrict__ w,
        const float* __restrict__ bias, const int* __restrict__ src,
        const int* __restrict__ rp, float* __restrict__ y) {
    __shared__ float tile[J_BLK][132];  // 132: 16B-aligned rows

    const int tid  = threadIdx.x;
    const int wid  = tid >> 6;
    const int lane = tid & 63;
    const int slot = lane >> 4;         // 0..3
    const int bl   = lane & 15;         // 16B chunk -> batch cols 8*bl .. 8*bl+7
    const int j0   = blockIdx.x * J_BLK;
    const int j    = j0 + wid;

    const int e0 = __builtin_amdgcn_readfirstlane(rp[j]);
    const int e1 = __builtin_amdgcn_readfirstlane(rp[j + 1]);

    float acc[8] = {0.f, 0.f, 0.f, 0.f, 0.f, 0.f, 0.f, 0.f};
    const char* xbase = (const char*)xTh + bl * 16;   // + row*256B

#pragma unroll 4
    for (int e = e0; e < e1; e += 4) {
        const int  ee    = e + slot;
        const bool valid = ee < e1;
        const int  ec    = valid ? ee : e0;           // e0 < e1 inside loop
        const int  s     = __builtin_nontemporal_load(src + ec);
        const float wt   = valid ? __builtin_nontemporal_load(w + ec) : 0.f;
        const float4 raw = *(const float4*)(xbase + (size_t)s * (B_DIM * 2));
        const __half2* hp = (const __half2*)&raw;
#pragma unroll
        for (int q = 0; q < 4; ++q) {
            const float2 f = __half22float2(hp[q]);
            acc[2 * q]     = fmaf(f.x, wt, acc[2 * q]);
            acc[2 * q + 1] = fmaf(f.y, wt, acc[2 * q + 1]);
        }
    }

    // Reduce over the 4 edge slots (lane bits 4..5).
#pragma unroll
    for (int m = 16; m <= 32; m <<= 1)
#pragma unroll
        for (int q = 0; q < 8; ++q) acc[q] += __shfl_xor(acc[q], m, 64);

    if (slot == 0) {                    // lanes 0..15 hold b = 8*bl .. 8*bl+7
#pragma unroll
        for (int q = 0; q < 8; ++q) tile[wid][8 * bl + q] = acc[q];
    }
    __syncthreads();

    // Coalesced epilogue: 8 consecutive lanes -> 8 consecutive j (32B segments).
    // y is written once -> non-temporal store (no L2 pollution).
#pragma unroll
    for (int i = tid; i < B_DIM * J_BLK; i += THREADS) {
        const int bb = i >> 3;
        const int jj = i & (J_BLK - 1);
        const float v = tile[jj][bb] + bias[j0 + jj];
        __builtin_nontemporal_store(fmaxf(v, 0.f), &y[(size_t)bb * N_OUT + (j0 + jj)]);
    }
}

// Fallback (no usable workspace): per-output wave, fp32 gathers from row-major x.
__global__ __launch_bounds__(THREADS) void sparse_layer_fallback(
        const float* __restrict__ x, const float* __restrict__ w,
        const float* __restrict__ bias, const int* __restrict__ src,
        const int* __restrict__ dst, float* __restrict__ y) {
    __shared__ float tile[J_BLK][130];
    __shared__ int   srp[J_BLK + 1];

    const int tid  = threadIdx.x;
    const int wid  = tid >> 6;
    const int lane = tid & 63;
    const int j0   = blockIdx.x * J_BLK;

    if (tid <= J_BLK) srp[tid] = lower_bound_dev(dst, N_EDGES, j0 + tid);
    __syncthreads();

    const int e0 = srp[wid], e1 = srp[wid + 1];
    const int b0 = lane * 2;
    float acc0 = 0.f, acc1 = 0.f;
    for (int e = e0; e < e1; ++e) {
        const int   s  = src[e];
        const float wt = w[e];
        acc0 = fmaf(x[(size_t)b0 * N_IN + s], wt, acc0);
        acc1 = fmaf(x[(size_t)(b0 + 1) * N_IN + s], wt, acc1);
    }
    tile[wid][b0]     = acc0;
    tile[wid][b0 + 1] = acc1;
    __syncthreads();
#pragma unroll
    for (int i = tid; i < B_DIM * J_BLK; i += THREADS) {
        const int bb = i >> 3;
        const int jj = i & (J_BLK - 1);
        const float v = tile[jj][bb] + bias[j0 + jj];
        y[(size_t)bb * N_OUT + (j0 + jj)] = fmaxf(v, 0.f);
    }
}

extern "C" void kernel_launch(void* const* d_in, const int* in_sizes, int n_in,
                              void* d_out, int out_size, void* d_ws, size_t ws_size,
                              hipStream_t stream) {
    const float* x    = (const float*)d_in[0];
    const float* w    = (const float*)d_in[1];
    const float* bias = (const float*)d_in[2];
    const int*   esrc = (const int*)d_in[3];
    const int*   edst = (const int*)d_in[4];
    float*       y    = (float*)d_out;

    // ws layout: rp [0, 64KB) | xTh [64KB, +4MB)
    const size_t XT_OFF   = 65536;
    const size_t XT_BYTES = (size_t)N_IN * B_DIM * sizeof(__half);

    const bool has_ws = ws_size >= XT_OFF + XT_BYTES;

    int*    rp  = (int*)d_ws;
    __half* xTh = (__half*)((char*)d_ws + XT_OFF);

    if (has_ws) {
        build_rowptr_kernel<<<(N_EDGES + 255) / 256, 256, 0, stream>>>(edst, rp);
        transpose_h_kernel<<<dim3(N_IN / 32, B_DIM / 64), dim3(32, 8), 0, stream>>>(x, xTh);
        sparse_layer_h<<<dim3(JGROUPS), THREADS, 0, stream>>>(xTh, w, bias, esrc, rp, y);
    } else {
        sparse_layer_fallback<<<dim3(N_OUT / J_BLK), THREADS, 0, stream>>>(x, w, bias, esrc, edst, y);
    }
}